// Round 4
// baseline (555.287 us; speedup 1.0000x reference)
//
#include <hip/hip_runtime.h>

// Edge softmax, round 4: coarse node-buckets + LDS segmented reduce.
//
// Lessons so far (counters):
//  r1: compact global atomics cap at ~180-190 G/s -> 25.6M+25.6M atomics = 295us.
//  r2: SPREADING atomic destinations -> 32B write-through each, 8x worse.
//  r3: exact-CSR scatter of 4B values to random slots -> 15x write amplification
//      (194MB for 12.8MB payload), 330us. Scatter frontiers must be few & local.
//
// This round:
//  - buckets of 64 nodes, x8 replica sub-segments keyed by blockIdx&7 (~XCD):
//    12.5K write frontiers (~800KB) stay L2-local, lines fill quickly -> ~1
//    writeback per line.
//  - k_bucket: one block per bucket; LDS atomicMax/atomicAdd accumulators
//    (64 nodes x 8 heads, [h][node] layout = conflict-free-ish). Heavy pass has
//    ZERO global atomics. Logits gathered as 32B-aligned float4x2 (no sector
//    amplification); second sweep re-gathers from L2/L3.

#define RREP    8
#define BSHIFT  6
#define BNODES  64

__device__ __forceinline__ unsigned enc_f32(float f) {
    unsigned u = __float_as_uint(f);
    return (u & 0x80000000u) ? ~u : (u | 0x80000000u);
}
__device__ __forceinline__ float dec_f32(unsigned u) {
    return __uint_as_float((u & 0x80000000u) ? (u & 0x7FFFFFFFu) : ~u);
}

__global__ __launch_bounds__(256)
void k_hist(const int* __restrict__ dst, unsigned* __restrict__ counts, int E) {
    int e = blockIdx.x * 256 + threadIdx.x;
    if (e < E) {
        int b = (dst[e] >> BSHIFT) * RREP + (blockIdx.x & (RREP - 1));
        atomicAdd(&counts[b], 1u);
    }
}

// single-block exclusive scan of counts[0..M) -> off[0..M], cur = off
__global__ __launch_bounds__(1024)
void k_scan(const unsigned* __restrict__ counts, unsigned* __restrict__ off,
            unsigned* __restrict__ cur, int M) {
    __shared__ unsigned tmp[1024];
    __shared__ unsigned carry;
    if (threadIdx.x == 0) carry = 0u;
    __syncthreads();
    for (int base = 0; base < M; base += 1024) {
        int j = base + threadIdx.x;
        unsigned v = (j < M) ? counts[j] : 0u;
        tmp[threadIdx.x] = v;
        __syncthreads();
        for (int o = 1; o < 1024; o <<= 1) {
            unsigned t = (threadIdx.x >= o) ? tmp[threadIdx.x - o] : 0u;
            __syncthreads();
            tmp[threadIdx.x] += t;
            __syncthreads();
        }
        if (j < M) {
            unsigned ex = tmp[threadIdx.x] - v + carry;
            off[j] = ex;
            cur[j] = ex;
        }
        unsigned tot = tmp[1023];
        __syncthreads();
        if (threadIdx.x == 0) carry += tot;
        __syncthreads();
    }
    if (threadIdx.x == 0) off[M] = carry;
}

__global__ __launch_bounds__(256)
void k_scatter2(const int* __restrict__ dst, unsigned* __restrict__ cur,
                unsigned* __restrict__ perm, int E) {
    int e = blockIdx.x * 256 + threadIdx.x;
    if (e < E) {
        int d = dst[e];
        int b = (d >> BSHIFT) * RREP + (blockIdx.x & (RREP - 1));
        unsigned p = atomicAdd(&cur[b], 1u);
        perm[p] = ((unsigned)(d & (BNODES - 1)) << 26) | (unsigned)e;
    }
}

// one block per bucket of 64 nodes: LDS max -> exp -> scores + LDS sum -> norm
__global__ __launch_bounds__(256)
void k_bucket(const float* __restrict__ logits, const unsigned* __restrict__ perm,
              const unsigned* __restrict__ off, float* __restrict__ scores,
              float* __restrict__ norm, int N) {
    __shared__ unsigned mEnc[8 * BNODES];   // [h][node]
    __shared__ float    sSum[8 * BNODES];   // [h][node]
    const int b = blockIdx.x;
    for (int j = threadIdx.x; j < 8 * BNODES; j += 256) {
        mEnc[j] = 0u;          // enc identity: any finite float encodes > 0
        sSum[j] = 0.0f;
    }
    const unsigned start = off[(unsigned)b * RREP];
    const unsigned end   = off[(unsigned)(b + 1) * RREP];
    __syncthreads();

    // sweep 1: segmented max into LDS
    for (unsigned c = start + threadIdx.x; c < end; c += 256) {
        unsigned pk = perm[c];
        unsigned e  = pk & 0x03FFFFFFu;
        unsigned ld = pk >> 26;
        const float4* lp = (const float4*)(logits + (size_t)e * 8);
        float4 x = lp[0], y = lp[1];
        atomicMax(&mEnc[0 * BNODES + ld], enc_f32(x.x));
        atomicMax(&mEnc[1 * BNODES + ld], enc_f32(x.y));
        atomicMax(&mEnc[2 * BNODES + ld], enc_f32(x.z));
        atomicMax(&mEnc[3 * BNODES + ld], enc_f32(x.w));
        atomicMax(&mEnc[4 * BNODES + ld], enc_f32(y.x));
        atomicMax(&mEnc[5 * BNODES + ld], enc_f32(y.y));
        atomicMax(&mEnc[6 * BNODES + ld], enc_f32(y.z));
        atomicMax(&mEnc[7 * BNODES + ld], enc_f32(y.w));
    }
    __syncthreads();

    // sweep 2: exp + scores store + segmented sum into LDS
    for (unsigned c = start + threadIdx.x; c < end; c += 256) {
        unsigned pk = perm[c];
        unsigned e  = pk & 0x03FFFFFFu;
        unsigned ld = pk >> 26;
        const float4* lp = (const float4*)(logits + (size_t)e * 8);
        float4 x = lp[0], y = lp[1];
        float s0 = __expf(x.x - dec_f32(mEnc[0 * BNODES + ld]));
        float s1 = __expf(x.y - dec_f32(mEnc[1 * BNODES + ld]));
        float s2 = __expf(x.z - dec_f32(mEnc[2 * BNODES + ld]));
        float s3 = __expf(x.w - dec_f32(mEnc[3 * BNODES + ld]));
        float s4 = __expf(y.x - dec_f32(mEnc[4 * BNODES + ld]));
        float s5 = __expf(y.y - dec_f32(mEnc[5 * BNODES + ld]));
        float s6 = __expf(y.z - dec_f32(mEnc[6 * BNODES + ld]));
        float s7 = __expf(y.w - dec_f32(mEnc[7 * BNODES + ld]));
        float4* sp = (float4*)(scores + (size_t)e * 8);
        sp[0] = make_float4(s0, s1, s2, s3);
        sp[1] = make_float4(s4, s5, s6, s7);
        atomicAdd(&sSum[0 * BNODES + ld], s0);
        atomicAdd(&sSum[1 * BNODES + ld], s1);
        atomicAdd(&sSum[2 * BNODES + ld], s2);
        atomicAdd(&sSum[3 * BNODES + ld], s3);
        atomicAdd(&sSum[4 * BNODES + ld], s4);
        atomicAdd(&sSum[5 * BNODES + ld], s5);
        atomicAdd(&sSum[6 * BNODES + ld], s6);
        atomicAdd(&sSum[7 * BNODES + ld], s7);
    }
    __syncthreads();

    // write norm [node][8]
    const int nodeBase = b << BSHIFT;
    for (int j = threadIdx.x; j < 8 * BNODES; j += 256) {
        int ld = j >> 3, h = j & 7;
        int node = nodeBase + ld;
        if (node < N) norm[(size_t)node * 8 + h] = sSum[h * BNODES + ld];
    }
}

// ---------- round-1 fallback (H != 8, tiny workspace, or E too large) ----------

__global__ void pass1_old(const float* __restrict__ logits, const int* __restrict__ dst,
                          unsigned* __restrict__ menc, int EH, int H) {
    int i = blockIdx.x * blockDim.x + threadIdx.x;
    if (i >= EH) return;
    int e = i / H, h = i - e * H;
    atomicMax(menc + (size_t)dst[e] * H + h, enc_f32(logits[i]));
}
__global__ void pass2_old(const float* __restrict__ logits, const int* __restrict__ dst,
                          const unsigned* __restrict__ menc, float* __restrict__ scores,
                          float* __restrict__ norm, int EH, int H) {
    int i = blockIdx.x * blockDim.x + threadIdx.x;
    if (i >= EH) return;
    int e = i / H, h = i - e * H;
    int d = dst[e];
    float s = __expf(logits[i] - dec_f32(menc[(size_t)d * H + h]));
    scores[i] = s;
    atomicAdd(norm + (size_t)d * H + h, s);
}

extern "C" void kernel_launch(void* const* d_in, const int* in_sizes, int n_in,
                              void* d_out, int out_size, void* d_ws, size_t ws_size,
                              hipStream_t stream) {
    const float* logits = (const float*)d_in[0];   // [E, H, 1] f32
    const int*   dst    = (const int*)d_in[1];     // [E] i32

    const int EH = in_sizes[0];
    const int E  = in_sizes[1];
    const int H  = EH / E;
    const int NH = out_size - EH;
    const int N  = NH / H;

    float* scores = (float*)d_out;          // [E,H]
    float* norm   = scores + EH;            // [N,H]

    const int NBKT = (N + BNODES - 1) >> BSHIFT;
    const int M    = NBKT * RREP;
    const size_t need = ((size_t)3 * M + 1 + (size_t)E) * sizeof(unsigned);

    if (H != 8 || E >= (1 << 26) || ws_size < need) {
        // fallback: round-1 atomic scheme
        unsigned* menc = (unsigned*)d_ws;
        hipMemsetAsync(menc, 0, (size_t)NH * 4, stream);
        hipMemsetAsync(norm, 0, (size_t)NH * 4, stream);
        int block = 256, grid = (EH + block - 1) / block;
        pass1_old<<<grid, block, 0, stream>>>(logits, dst, menc, EH, H);
        pass2_old<<<grid, block, 0, stream>>>(logits, dst, menc, scores, norm, EH, H);
        return;
    }

    unsigned* counts = (unsigned*)d_ws;      // [M]
    unsigned* off    = counts + M;           // [M+1]
    unsigned* cur    = off + M + 1;          // [M]
    unsigned* perm   = cur + M;              // [E]

    hipMemsetAsync(counts, 0, (size_t)M * 4, stream);

    const int gridE = (E + 255) / 256;

    k_hist    <<<gridE, 256, 0, stream>>>(dst, counts, E);
    k_scan    <<<1, 1024, 0, stream>>>(counts, off, cur, M);
    k_scatter2<<<gridE, 256, 0, stream>>>(dst, cur, perm, E);
    k_bucket  <<<NBKT, 256, 0, stream>>>(logits, perm, off, scores, norm, N);
}